// Round 1
// baseline (121.105 us; speedup 1.0000x reference)
//
#include <hip/hip_runtime.h>

#define N 16384
#define CHUNKS 8
#define CHUNK 2048   // N / CHUNKS
#define BLK 256

// C = SCALE * log2(e), so sigmoid(SCALE*(xj - xi)) = 1 / (1 + exp2(C*xi - C*xj))
__device__ __forceinline__ float sig_from_arg(float arg) {
    // arg = a_i - b_j ; sigma = 1/(1+2^arg)
    return __builtin_amdgcn_rcpf(1.0f + __builtin_amdgcn_exp2f(arg));
}

__global__ __launch_bounds__(BLK) void soft_rank_partial(
    const float* __restrict__ pred, const float* __restrict__ target,
    float* __restrict__ partials) {
    const int arr   = blockIdx.z;              // 0 = pred, 1 = target
    const float* __restrict__ x = arr ? target : pred;
    const int chunk = blockIdx.y;              // 0..CHUNKS-1
    const int i     = blockIdx.x * BLK + threadIdx.x;

    __shared__ float bsh[CHUNK];
    const float C = 14.426950408889634f;       // 10 * log2(e)
    const int j0 = chunk * CHUNK;
    for (int t = threadIdx.x; t < CHUNK; t += BLK)
        bsh[t] = x[j0 + t] * C;
    __syncthreads();

    const float a = x[i] * C;
    float acc0 = 0.f, acc1 = 0.f, acc2 = 0.f, acc3 = 0.f;
    const float4* __restrict__ b4 = (const float4*)bsh;
    #pragma unroll 4
    for (int j4 = 0; j4 < CHUNK / 4; ++j4) {
        float4 b = b4[j4];                     // broadcast ds_read_b128
        acc0 += sig_from_arg(a - b.x);
        acc1 += sig_from_arg(a - b.y);
        acc2 += sig_from_arg(a - b.z);
        acc3 += sig_from_arg(a - b.w);
    }
    partials[((size_t)(arr * CHUNKS + chunk)) * N + i] = (acc0 + acc1) + (acc2 + acc3);
}

__global__ __launch_bounds__(BLK) void reduce_ranks(
    const float* __restrict__ partials, float* __restrict__ ranks) {
    const int idx = blockIdx.x * BLK + threadIdx.x;   // 0 .. 2N-1
    const int arr = idx >> 14;                        // idx / N
    const int i   = idx & (N - 1);                    // idx % N
    float s = 1.0f;                                   // the "+ 1.0" in soft_rank
    #pragma unroll
    for (int c = 0; c < CHUNKS; ++c)
        s += partials[((size_t)(arr * CHUNKS + c)) * N + i];
    ranks[idx] = s;
}

__global__ __launch_bounds__(BLK) void finalize(
    const float* __restrict__ ranks, float* __restrict__ out) {
    const int tid = threadIdx.x;
    const float* __restrict__ pr = ranks;
    const float* __restrict__ tr = ranks + N;

    double sp = 0.0, st = 0.0, spp = 0.0, stt = 0.0, spt = 0.0;
    for (int i = tid; i < N; i += BLK) {
        double p = (double)pr[i];
        double t = (double)tr[i];
        sp  += p;    st  += t;
        spp += p * p; stt += t * t; spt += p * t;
    }

    __shared__ double sh[5][BLK];
    sh[0][tid] = sp; sh[1][tid] = st; sh[2][tid] = spp;
    sh[3][tid] = stt; sh[4][tid] = spt;
    __syncthreads();
    for (int s = BLK / 2; s > 0; s >>= 1) {
        if (tid < s) {
            #pragma unroll
            for (int k = 0; k < 5; ++k) sh[k][tid] += sh[k][tid + s];
        }
        __syncthreads();
    }
    if (tid == 0) {
        const double n  = (double)N;
        const double mp = sh[0][0] / n;
        const double mt = sh[1][0] / n;
        const double cov  = sh[4][0] / n - mp * mt;
        const double varp = sh[2][0] / n - mp * mp;
        const double vart = sh[3][0] / n - mt * mt;
        const double corr = cov / (sqrt(varp + 1e-8) * sqrt(vart + 1e-8));
        out[0] = (float)(1.0 - corr);
    }
}

extern "C" void kernel_launch(void* const* d_in, const int* in_sizes, int n_in,
                              void* d_out, int out_size, void* d_ws, size_t ws_size,
                              hipStream_t stream) {
    const float* pred   = (const float*)d_in[0];
    const float* target = (const float*)d_in[1];
    float* out = (float*)d_out;

    // workspace layout (floats): partials[2*CHUNKS*N], ranks[2*N]
    float* partials = (float*)d_ws;
    float* ranks    = partials + (size_t)2 * CHUNKS * N;

    dim3 gridA(N / BLK, CHUNKS, 2);
    soft_rank_partial<<<gridA, BLK, 0, stream>>>(pred, target, partials);
    reduce_ranks<<<(2 * N) / BLK, BLK, 0, stream>>>(partials, ranks);
    finalize<<<1, BLK, 0, stream>>>(ranks, out);
}

// Round 2
// 79.179 us; speedup vs baseline: 1.5295x; 1.5295x over previous
//
#include <hip/hip_runtime.h>

#define N 16384
#define CHUNKS 8
#define CHUNK 2048   // N / CHUNKS
#define BLK 256

// pair[i,j] = sigmoid((x_j - x_i)*10) = 1/(1 + 2^(C*x_i - C*x_j)),  C = 10*log2(e)
// Factorization: 2^(A_i - B_j) = EA_i * EB_j,  EA_i = 2^(C*x_i), EB_j = 2^(-C*x_j).
// Inner loop per pair: v_fma + v_rcp + v_add  (exp2 amortized out of the N^2 loop).

__global__ __launch_bounds__(BLK) void soft_rank_partial(
    const float* __restrict__ pred, const float* __restrict__ target,
    float* __restrict__ partials) {
    const int arr   = blockIdx.z;              // 0 = pred, 1 = target
    const float* __restrict__ x = arr ? target : pred;
    const int chunk = blockIdx.y;              // 0..CHUNKS-1
    const int i     = blockIdx.x * BLK + threadIdx.x;

    __shared__ float bsh[CHUNK];
    const float C = 14.426950408889634f;       // 10 * log2(e)
    const int j0 = chunk * CHUNK;
    for (int t = threadIdx.x; t < CHUNK; t += BLK)
        bsh[t] = __builtin_amdgcn_exp2f(-C * x[j0 + t]);   // EB_j
    __syncthreads();

    const float ea = __builtin_amdgcn_exp2f(C * x[i]);     // EA_i
    float acc0 = 0.f, acc1 = 0.f, acc2 = 0.f, acc3 = 0.f;
    const float4* __restrict__ b4 = (const float4*)bsh;
    #pragma unroll 4
    for (int j4 = 0; j4 < CHUNK / 4; ++j4) {
        float4 b = b4[j4];                     // broadcast ds_read_b128
        acc0 += __builtin_amdgcn_rcpf(__builtin_fmaf(ea, b.x, 1.0f));
        acc1 += __builtin_amdgcn_rcpf(__builtin_fmaf(ea, b.y, 1.0f));
        acc2 += __builtin_amdgcn_rcpf(__builtin_fmaf(ea, b.z, 1.0f));
        acc3 += __builtin_amdgcn_rcpf(__builtin_fmaf(ea, b.w, 1.0f));
    }
    partials[((size_t)(arr * CHUNKS + chunk)) * N + i] = (acc0 + acc1) + (acc2 + acc3);
}

__global__ __launch_bounds__(BLK) void reduce_ranks(
    const float* __restrict__ partials, float* __restrict__ ranks) {
    const int idx = blockIdx.x * BLK + threadIdx.x;   // 0 .. 2N-1
    const int arr = idx >> 14;                        // idx / N
    const int i   = idx & (N - 1);                    // idx % N
    float s = 1.0f;                                   // the "+ 1.0" in soft_rank
    #pragma unroll
    for (int c = 0; c < CHUNKS; ++c)
        s += partials[((size_t)(arr * CHUNKS + c)) * N + i];
    ranks[idx] = s;
}

__global__ __launch_bounds__(BLK) void finalize(
    const float* __restrict__ ranks, float* __restrict__ out) {
    const int tid = threadIdx.x;
    const float* __restrict__ pr = ranks;
    const float* __restrict__ tr = ranks + N;

    double sp = 0.0, st = 0.0, spp = 0.0, stt = 0.0, spt = 0.0;
    for (int i = tid; i < N; i += BLK) {
        double p = (double)pr[i];
        double t = (double)tr[i];
        sp  += p;    st  += t;
        spp += p * p; stt += t * t; spt += p * t;
    }

    __shared__ double sh[5][BLK];
    sh[0][tid] = sp; sh[1][tid] = st; sh[2][tid] = spp;
    sh[3][tid] = stt; sh[4][tid] = spt;
    __syncthreads();
    for (int s = BLK / 2; s > 0; s >>= 1) {
        if (tid < s) {
            #pragma unroll
            for (int k = 0; k < 5; ++k) sh[k][tid] += sh[k][tid + s];
        }
        __syncthreads();
    }
    if (tid == 0) {
        const double n  = (double)N;
        const double mp = sh[0][0] / n;
        const double mt = sh[1][0] / n;
        const double cov  = sh[4][0] / n - mp * mt;
        const double varp = sh[2][0] / n - mp * mp;
        const double vart = sh[3][0] / n - mt * mt;
        const double corr = cov / (sqrt(varp + 1e-8) * sqrt(vart + 1e-8));
        out[0] = (float)(1.0 - corr);
    }
}

extern "C" void kernel_launch(void* const* d_in, const int* in_sizes, int n_in,
                              void* d_out, int out_size, void* d_ws, size_t ws_size,
                              hipStream_t stream) {
    const float* pred   = (const float*)d_in[0];
    const float* target = (const float*)d_in[1];
    float* out = (float*)d_out;

    // workspace layout (floats): partials[2*CHUNKS*N], ranks[2*N]
    float* partials = (float*)d_ws;
    float* ranks    = partials + (size_t)2 * CHUNKS * N;

    dim3 gridA(N / BLK, CHUNKS, 2);
    soft_rank_partial<<<gridA, BLK, 0, stream>>>(pred, target, partials);
    reduce_ranks<<<(2 * N) / BLK, BLK, 0, stream>>>(partials, ranks);
    finalize<<<1, BLK, 0, stream>>>(ranks, out);
}

// Round 3
// 54.291 us; speedup vs baseline: 2.2307x; 1.4584x over previous
//
#include <hip/hip_runtime.h>

#define N 16384
#define CHUNKS 8
#define CHUNK 2048   // N / CHUNKS
#define BLK 256

typedef float v2f __attribute__((ext_vector_type(2)));

// sigma_ij = 1/(1 + ea_i * eb_j),  ea = 2^(C*x_i), eb = 2^(-C*x_j), C = 10*log2(e).
// Batched reciprocal: sum_i 1/p_i = (sum_i prod_{j!=i} p_j) / prod_j p_j -> 1 rcp / 8 pairs.
// p clamped to [1, 2^15] so the 8-product <= 2^120 stays finite (clamp error <= 2^-15/pair).

__device__ __forceinline__ v2f pfma(v2f a, v2f b, v2f c) {
    return __builtin_elementwise_fma(a, b, c);
}
__device__ __forceinline__ v2f pmin(v2f a, v2f b) {
    return __builtin_elementwise_min(a, b);
}

// 16 consecutive j's (4 float4 from LDS). Lane .x covers even pair-slots, .y odd.
__device__ __forceinline__ void batch16(v2f ea2, v2f one2, v2f cl2,
                                        float4 u0, float4 u1, float4 u2, float4 u3,
                                        v2f& acc) {
    v2f P0 = pmin(pfma(ea2, (v2f){u0.x, u0.y}, one2), cl2);
    v2f P1 = pmin(pfma(ea2, (v2f){u0.z, u0.w}, one2), cl2);
    v2f P2 = pmin(pfma(ea2, (v2f){u1.x, u1.y}, one2), cl2);
    v2f P3 = pmin(pfma(ea2, (v2f){u1.z, u1.w}, one2), cl2);
    v2f P4 = pmin(pfma(ea2, (v2f){u2.x, u2.y}, one2), cl2);
    v2f P5 = pmin(pfma(ea2, (v2f){u2.z, u2.w}, one2), cl2);
    v2f P6 = pmin(pfma(ea2, (v2f){u3.x, u3.y}, one2), cl2);
    v2f P7 = pmin(pfma(ea2, (v2f){u3.z, u3.w}, one2), cl2);

    v2f S01 = P0 + P1, Q01 = P0 * P1;
    v2f S23 = P2 + P3, Q23 = P2 * P3;
    v2f S45 = P4 + P5, Q45 = P4 * P5;
    v2f S67 = P6 + P7, Q67 = P6 * P7;
    v2f Q0123 = Q01 * Q23, Q4567 = Q45 * Q67;
    v2f PP = Q0123 * Q4567;                       // <= 2^120, finite
    v2f N1 = pfma(Q01, S23, Q23 * S01);           // sum of 3-prods, batch halves
    v2f N2 = pfma(Q45, S67, Q67 * S45);
    v2f NUM = pfma(Q0123, N2, Q4567 * N1);        // sum_i prod_{j!=i} p_j
    v2f R = { __builtin_amdgcn_rcpf(PP.x), __builtin_amdgcn_rcpf(PP.y) };
    acc = pfma(NUM, R, acc);
}

__global__ __launch_bounds__(BLK) void soft_rank_partial(
    const float* __restrict__ pred, const float* __restrict__ target,
    float* __restrict__ partials) {
    const int arr   = blockIdx.z;              // 0 = pred, 1 = target
    const float* __restrict__ x = arr ? target : pred;
    const int chunk = blockIdx.y;              // 0..CHUNKS-1
    const int i     = blockIdx.x * BLK + threadIdx.x;

    __shared__ float bsh[CHUNK];
    const float C = 14.426950408889634f;       // 10 * log2(e)
    const int j0 = chunk * CHUNK;
    for (int t = threadIdx.x; t < CHUNK; t += BLK)
        bsh[t] = __builtin_amdgcn_exp2f(-C * x[j0 + t]);   // EB_j
    __syncthreads();

    const float ea = __builtin_amdgcn_exp2f(C * x[i]);     // EA_i
    const v2f ea2  = {ea, ea};
    const v2f one2 = {1.0f, 1.0f};
    const v2f cl2  = {32768.0f, 32768.0f};     // 2^15 clamp

    v2f acc0 = {0.f, 0.f}, acc1 = {0.f, 0.f};
    const float4* __restrict__ b4 = (const float4*)bsh;
    #pragma unroll 2
    for (int it = 0; it < CHUNK / 32; ++it) {
        float4 u0 = b4[8*it+0], u1 = b4[8*it+1], u2 = b4[8*it+2], u3 = b4[8*it+3];
        float4 w0 = b4[8*it+4], w1 = b4[8*it+5], w2 = b4[8*it+6], w3 = b4[8*it+7];
        batch16(ea2, one2, cl2, u0, u1, u2, u3, acc0);
        batch16(ea2, one2, cl2, w0, w1, w2, w3, acc1);
    }
    v2f acc = acc0 + acc1;
    partials[((size_t)(arr * CHUNKS + chunk)) * N + i] = acc.x + acc.y;
}

// ranks from partials + per-block f64 moment partials (deterministic tree).
__global__ __launch_bounds__(256) void rank_moments(
    const float* __restrict__ partials, double* __restrict__ mom) {
    const int tid = threadIdx.x;
    const int i   = blockIdx.x * 256 + tid;           // 0..N-1
    float pr = 1.0f, tr = 1.0f;                       // the "+1.0" in soft_rank
    #pragma unroll
    for (int c = 0; c < CHUNKS; ++c) {
        pr += partials[(size_t)c * N + i];
        tr += partials[(size_t)(CHUNKS + c) * N + i];
    }
    double p = (double)pr, t = (double)tr;
    double v0 = p, v1 = t, v2 = p * p, v3 = t * t, v4 = p * t;

    __shared__ double sh[5][256];
    sh[0][tid] = v0; sh[1][tid] = v1; sh[2][tid] = v2;
    sh[3][tid] = v3; sh[4][tid] = v4;
    __syncthreads();
    for (int s = 128; s > 0; s >>= 1) {
        if (tid < s) {
            #pragma unroll
            for (int k = 0; k < 5; ++k) sh[k][tid] += sh[k][tid + s];
        }
        __syncthreads();
    }
    if (tid == 0) {
        #pragma unroll
        for (int k = 0; k < 5; ++k) mom[blockIdx.x * 5 + k] = sh[k][0];
    }
}

__global__ void final_corr(const double* __restrict__ mom, float* __restrict__ out) {
    const int l = threadIdx.x;                        // 0..63, one wave, 64 blocks of mom
    double v[5];
    #pragma unroll
    for (int k = 0; k < 5; ++k) v[k] = mom[l * 5 + k];
    #pragma unroll
    for (int off = 32; off > 0; off >>= 1) {
        #pragma unroll
        for (int k = 0; k < 5; ++k) v[k] += __shfl_down(v[k], off);
    }
    if (l == 0) {
        const double n  = (double)N;
        const double mp = v[0] / n;
        const double mt = v[1] / n;
        const double cov  = v[4] / n - mp * mt;
        const double varp = v[2] / n - mp * mp;
        const double vart = v[3] / n - mt * mt;
        const double corr = cov / (sqrt(varp + 1e-8) * sqrt(vart + 1e-8));
        out[0] = (float)(1.0 - corr);
    }
}

extern "C" void kernel_launch(void* const* d_in, const int* in_sizes, int n_in,
                              void* d_out, int out_size, void* d_ws, size_t ws_size,
                              hipStream_t stream) {
    const float* pred   = (const float*)d_in[0];
    const float* target = (const float*)d_in[1];
    float* out = (float*)d_out;

    // ws layout: partials[2*CHUNKS*N] floats (1 MB), then 64*5 doubles (8B-aligned).
    float*  partials = (float*)d_ws;
    double* mom      = (double*)((char*)d_ws + (size_t)2 * CHUNKS * N * sizeof(float));

    dim3 gridA(N / BLK, CHUNKS, 2);
    soft_rank_partial<<<gridA, BLK, 0, stream>>>(pred, target, partials);
    rank_moments<<<N / 256, 256, 0, stream>>>(partials, mom);
    final_corr<<<1, 64, 0, stream>>>(mom, out);
}